// Round 6
// baseline (841.923 us; speedup 1.0000x reference)
//
#include <hip/hip_runtime.h>
#include <hip/hip_bf16.h>

using bf16 = __hip_bfloat16;
typedef __attribute__((ext_vector_type(8))) short s8v;
typedef __attribute__((ext_vector_type(4))) float f4v;
typedef __attribute__((ext_vector_type(16))) float f16v;

static constexpr int Bb = 2, Hh = 48, Ww = 96;
static constexpr int HW = Hh * Ww;              // 4608
static constexpr int DD = 49, Nn = Bb * DD;     // 98
static constexpr int H2 = 24, W2 = 48, HW2 = H2 * W2;

// ---------------- workspace layout (bytes) ----------------
static constexpr size_t off_wf1a = 0;                 // 221184
static constexpr size_t off_wf1b = 221184;            // 221184
static constexpr size_t off_wf3  = 442368;            // 294912
static constexpr size_t off_wf2  = 737280;            // 221184
static constexpr size_t off_wf4  = 958464;            // 147456
static constexpr size_t off_wf5  = 1105920;           // 65536
static constexpr size_t off_f1t  = 1171456;           // bf16 padded [2][50][98][128] = 2508800
static constexpr size_t off_y1a  = 3680256;           // f32 [2][4608][96] = 3538944
static constexpr size_t off_stats= 7219200;           // 5*2048
static constexpr size_t off_big  = 7229440;           // shared region 102961152
static constexpr size_t off_f2s  = off_big;           // bf16 padded half [49][50][98][128] = 61465600
static constexpr size_t off_f2tb = off_big + 61465600;// bf16 [2][4608][128] = 2359296
static constexpr size_t off_y2   = off_big;                   // bf16 [98][1152][128]
static constexpr size_t off_y3   = off_big + 28901376;        // bf16 [98][1152][128]
static constexpr size_t off_y4   = off_big + 57802752;        // bf16 [98][1152][64]
static constexpr size_t off_y5   = off_big + 72253440;        // bf16 [98][4608][32]
static constexpr size_t off_y6   = off_big + 101154816;       // f32 [98][4608]
static constexpr size_t off_y1   = 110190592;         // bf16 [98][4608][96] = 86704128
static constexpr size_t WS_NEEDED = 196894720;

// ---------------- helpers ----------------
__device__ __forceinline__ float bf2f(unsigned short h) {
  return __uint_as_float(((unsigned)h) << 16);
}
__device__ __forceinline__ unsigned short f2bf(float f) {
  __hip_bfloat16 h = __float2bfloat16(f);
  union { __hip_bfloat16 x; unsigned short u; } cv; cv.x = h; return cv.u;
}
template<bool EN>
__device__ __forceinline__ uint4 bn8(uint4 v, const float* a, const float* b, int c0) {
  if constexpr (!EN) return v;
  union { uint4 u; unsigned short h[8]; } X; X.u = v;
#pragma unroll
  for (int i = 0; i < 8; ++i) {
    float f = fmaxf(bf2f(X.h[i]) * a[c0 + i] + b[c0 + i], 0.f);
    X.h[i] = f2bf(f);
  }
  return X.u;
}
__device__ __forceinline__ s8v as_s8v(uint4 v) {
  union { uint4 u; s8v s; } cv; cv.u = v; return cv.s;
}
__device__ __forceinline__ int swz(int icl) { return ((icl >> 1) ^ (icl >> 3)) & 3; }
__device__ __forceinline__ int swz6(int cell) { return (cell ^ (cell >> 2)) & 3; }

// ---------------- small utility kernels ----------------
__global__ __launch_bounds__(256) void zero_k(float* __restrict__ p, int n) {
  int i = blockIdx.x * 256 + threadIdx.x;
  if (i < n) p[i] = 0.f;
}

// zero halo border cells of padded f2s half [49][50][98][128]
__global__ __launch_bounds__(256) void border0_k(bf16* __restrict__ f2s) {
  int idx = blockIdx.x * 256 + threadIdx.x;
  if (idx >= 49 * 292) return;
  int c2 = idx % 292, n = idx / 292;
  int r, c;
  if (c2 < 98) { r = 0; c = c2; }
  else if (c2 < 196) { r = 49; c = c2 - 98; }
  else if (c2 < 244) { r = c2 - 196 + 1; c = 0; }
  else { r = c2 - 244 + 1; c = 97; }
  uint4* p = (uint4*)(f2s + ((size_t)(n * 50 + r) * 98 + c) * 128);
  uint4 z = make_uint4(0u, 0u, 0u, 0u);
#pragma unroll
  for (int i = 0; i < 16; ++i) p[i] = z;
}

// f2 [2][128][4608] f32 -> f2tb [2][4608][128] bf16
__global__ __launch_bounds__(256) void tr_f2b_k(const float* __restrict__ f2, bf16* __restrict__ f2tb) {
  int o = blockIdx.x * 256 + threadIdx.x;
  if (o >= 2 * HW * 16) return;
  int c8 = o & 15; int pos = (o >> 4) % HW; int b = o / (HW * 16);
  union { uint4 u; unsigned short h[8]; } Y;
#pragma unroll
  for (int i = 0; i < 8; ++i) Y.h[i] = f2bf(f2[((size_t)(b * 128 + c8 * 8 + i)) * HW + pos]);
  *(uint4*)(f2tb + ((size_t)b * HW + pos) * 128 + c8 * 8) = Y.u;
}

// f1 [2][128][4608] f32 -> f1t padded [2][50][98][128] bf16 (interior only)
__global__ __launch_bounds__(256) void tr_f1_k(const float* __restrict__ f1, bf16* __restrict__ f1t) {
  int o = blockIdx.x * 256 + threadIdx.x;
  if (o >= 2 * HW * 16) return;
  int c8 = o & 15; int pos = (o >> 4) % HW; int b = o / (HW * 16);
  int h = pos / Ww, w = pos % Ww;
  union { uint4 u; unsigned short h8[8]; } Y;
#pragma unroll
  for (int i = 0; i < 8; ++i) Y.h8[i] = f2bf(f1[((size_t)(b * 128 + c8 * 8 + i)) * HW + pos]);
  *(uint4*)(f1t + ((size_t)(b * 50 + h + 1) * 98 + (w + 1)) * 128 + c8 * 8) = Y.u;
}

// weight prep: frag-ordered for 32x32x16 path.  [khw][cih][ks][nt][lh][ocl]x8bf16
__global__ __launch_bounds__(256)
void prep32_k(const float* __restrict__ w, uint4* __restrict__ wf, int NT, int CINT, int ciOff) {
  int idx = blockIdx.x * 256 + threadIdx.x;
  int total = 9 * 2 * 4 * NT * 64;
  if (idx >= total) return;
  int ocl = idx & 31; int lh = (idx >> 5) & 1;
  int q = idx >> 6; int nt = q % NT; int rest = q / NT;
  int ks = rest & 3; int cih = (rest >> 2) & 1; int khw = rest >> 3;
  int oc = nt * 32 + ocl;
  union { uint4 u; unsigned short h[8]; } Y;
#pragma unroll
  for (int i = 0; i < 8; ++i) {
    int ci = ciOff + cih * 64 + ks * 16 + lh * 8 + i;
    Y.h[i] = f2bf(w[((size_t)oc * CINT + ci) * 9 + khw]);
  }
  wf[idx] = Y.u;
}

// frag-ordered for 16x16x32 path.  [khw][st][ks][nt][lg][ocl]x8bf16
__global__ __launch_bounds__(256)
void prep16_k(const float* __restrict__ w, uint4* __restrict__ wf, int NT, int CINT,
              int NSTAGE, int CPS, int KPS) {
  int idx = blockIdx.x * 256 + threadIdx.x;
  int total = 9 * NSTAGE * KPS * NT * 64;
  if (idx >= total) return;
  int ocl = idx & 15; int lg = (idx >> 4) & 3;
  int q = idx >> 6; int nt = q % NT; int q2 = q / NT;
  int ks = q2 % KPS; int q3 = q2 / KPS;
  int st = q3 % NSTAGE; int khw = q3 / NSTAGE;
  int oc = nt * 16 + ocl;
  union { uint4 u; unsigned short h[8]; } Y;
#pragma unroll
  for (int i = 0; i < 8; ++i) {
    int ci = st * CPS + ks * 32 + lg * 8 + i;
    Y.h[i] = f2bf(w[((size_t)oc * CINT + ci) * 9 + khw]);
  }
  wf[idx] = Y.u;
}

// w5 [64ci][32oc][4][4] -> frag-ordered [p][ks][nt][lg][ocl]x8
__global__ __launch_bounds__(256)
void prep_w5_k(const float* __restrict__ w5, uint4* __restrict__ wf) {
  int idx = blockIdx.x * 256 + threadIdx.x;
  if (idx >= 4096) return;
  int ocl = idx & 15; int lg = (idx >> 4) & 3;
  int nt = (idx >> 6) & 1; int ks = (idx >> 7) & 7; int p = idx >> 10;
  int ph = p >> 1, pw = p & 1;
  int t = ks >> 2, u = (ks >> 1) & 1;
  int kh = 3 - ph - 2 * t, kw = 3 - pw - 2 * u;
  int oc = nt * 16 + ocl;
  union { uint4 u4; unsigned short h[8]; } Y;
#pragma unroll
  for (int i = 0; i < 8; ++i) {
    int ci = (ks & 1) * 32 + lg * 8 + i;
    Y.h[i] = f2bf(w5[(((size_t)ci * 32 + oc) * 4 + kh) * 4 + kw]);
  }
  wf[idx] = Y.u4;
}

// ---------------- correlation sampling -> padded f2s half (bf16) ----------------
__global__ __launch_bounds__(256)
void sample_k(const bf16* __restrict__ f2tb, const float* __restrict__ coords,
              bf16* __restrict__ f2s, int half) {
  int wv = blockIdx.x * 4 + (threadIdx.x >> 6);
  int lane = threadIdx.x & 63;
  int p0 = wv * 32;
  const unsigned* src = (const unsigned*)f2tb + (size_t)half * HW * 64;
  unsigned* dst = (unsigned*)f2s;
  for (int k = 0; k < 32; ++k) {
    int P = p0 + k;
    int hw = P % HW; int nl = P / HW;   // nl = d, 0..48
    float gx = coords[(size_t)half * 2 * HW + hw] + (float)(nl / 7 - 3);
    float gy = coords[((size_t)half * 2 + 1) * HW + hw] + (float)(nl % 7 - 3);
    float x0f = floorf(gx), y0f = floorf(gy);
    float wx = gx - x0f, wy = gy - y0f;
    int x0 = (int)x0f, y0 = (int)y0f;
    float r0 = 0.f, r1 = 0.f;
#pragma unroll
    for (int c = 0; c < 4; ++c) {
      int xi = x0 + (c & 1), yi = y0 + (c >> 1);
      float wgt = ((c & 1) ? wx : 1.f - wx) * ((c >> 1) ? wy : 1.f - wy);
      if (xi < 0 || xi >= Ww || yi < 0 || yi >= Hh) wgt = 0.f;
      int xc = min(max(xi, 0), Ww - 1), yc = min(max(yi, 0), Hh - 1);
      unsigned pv = src[(size_t)(yc * Ww + xc) * 64 + lane];
      r0 += wgt * bf2f((unsigned short)(pv & 0xffff));
      r1 += wgt * bf2f((unsigned short)(pv >> 16));
    }
    int h = hw / Ww, w = hw % Ww;
    unsigned pack = (unsigned)f2bf(r0) | ((unsigned)f2bf(r1) << 16);
    dst[((size_t)(nl * 50 + h + 1) * 98 + (w + 1)) * 64 + lane] = pack;
  }
}

// ---------------- 32x32x16 MFMA conv, global_load_lds staging (padded input) ----------------
// Input: padded [(N)][(H+2)][(W+2)][128] bf16, no bounds checks. Double-buffered LDS,
// one barrier per 32-ch K-slice; weights direct from global (L2-resident).
template<int COUT, int NT, int MT, int NB, int GR, int GC, bool OUTF32, bool HAS_BASE, bool HAS_STATS>
__global__ __launch_bounds__(((GR * GC) / MT) * (NT / NB) * 64, 3)
void conv32gll_k(const bf16* __restrict__ in, const uint4* __restrict__ wf,
                 void* __restrict__ outv, const float* __restrict__ base,
                 float* __restrict__ stats, int N, int H, int W) {
  constexpr int NW = ((GR * GC) / MT) * (NT / NB);
  constexpr int BR = GR * 2, BC = GC * 16;
  constexpr int IR = BR + 2, IC = BC + 2;
  constexpr int NGRAN = IR * IC * 4;
  constexpr int NCH = (NGRAN + 63) / 64;        // chunks of 64 granules
  constexpr int BUFB = NCH * 1024;
  constexpr int NCHW = (NCH + NW - 1) / NW;
  __shared__ __align__(16) char lds[2 * BUFB];

  const int tid = threadIdx.x;
  const int lane = tid & 63;
  const int wv = tid >> 6;
  const int lm = lane & 31, lh = lane >> 5;
  const int dh = lm >> 4, dw = lm & 15;
  constexpr int NG = NT / NB;
  const int mg = wv / NG, ng = wv % NG;

  const int tW = W / BC, tH = H / BR;
  const int tile = blockIdx.x % (tH * tW);
  const int n = blockIdx.x / (tH * tW);
  const int oh0 = (tile / tW) * BR, ow0 = (tile % tW) * BC;
  const int PW = W + 2, PH = H + 2;

  // per-lane source offsets (elems) for this wave's chunks
  int pixoff[NCHW];
#pragma unroll
  for (int k = 0; k < NCHW; ++k) {
    int c = wv + k * NW;
    int gi = c * 64 + lane;
    int cell = gi >> 2; if (cell >= IR * IC) cell = IR * IC - 1;
    int slot = gi & 3;
    int row = cell / IC, col = cell % IC;
    pixoff[k] = ((n * PH + oh0 + row) * PW + ow0 + col) * 128 + (slot ^ swz(col)) * 8;
  }

  int trA[MT], tcA[MT];
#pragma unroll
  for (int i = 0; i < MT; ++i) { int mt = mg * MT + i; trA[i] = mt / GC; tcA[i] = mt % GC; }

  f16v acc[MT][NB];
#pragma unroll
  for (int i = 0; i < MT; ++i)
#pragma unroll
    for (int j = 0; j < NB; ++j)
#pragma unroll
      for (int r = 0; r < 16; ++r) acc[i][j][r] = 0.f;

  // prologue: stage slice 0 into buf 0
#pragma unroll
  for (int k = 0; k < NCHW; ++k) {
    int c = wv + k * NW;
    if (c < NCH)
      __builtin_amdgcn_global_load_lds((const void*)(in + (size_t)pixoff[k]),
                                       (void*)(lds + c * 1024), 16, 0, 0);
  }
  __syncthreads();

#pragma unroll
  for (int ksl = 0; ksl < 4; ++ksl) {
    if (ksl < 3) {
#pragma unroll
      for (int k = 0; k < NCHW; ++k) {
        int c = wv + k * NW;
        if (c < NCH)
          __builtin_amdgcn_global_load_lds(
              (const void*)(in + (size_t)pixoff[k] + (ksl + 1) * 32),
              (void*)(lds + ((ksl + 1) & 1) * BUFB + c * 1024), 16, 0, 0);
      }
    }
    const char* bufp = lds + (ksl & 1) * BUFB;
#pragma unroll
    for (int khw = 0; khw < 9; ++khw) {
      const int kh = khw / 3, kw = khw % 3;
      const uint4* wfp = wf + (size_t)(khw * 2 + (ksl >> 1)) * (NT * 256);
#pragma unroll
      for (int ks = 0; ks < 2; ++ks) {
        s8v Af[MT], Bf[NB];
#pragma unroll
        for (int i = 0; i < MT; ++i) {
          int rl = trA[i] * 2 + dh + kh;
          int cl = tcA[i] * 16 + dw + kw;
          int g = (ks * 2 + lh) ^ swz(cl);
          Af[i] = *(const s8v*)(bufp + (rl * IC + cl) * 64 + g * 16);
        }
        int ks4 = (ksl & 1) * 2 + ks;
#pragma unroll
        for (int j = 0; j < NB; ++j)
          Bf[j] = as_s8v(wfp[(ks4 * NT + ng * NB + j) * 64 + lane]);
#pragma unroll
        for (int i = 0; i < MT; ++i)
#pragma unroll
          for (int j = 0; j < NB; ++j)
            acc[i][j] = __builtin_amdgcn_mfma_f32_32x32x16_bf16(Af[i], Bf[j], acc[i][j], 0, 0, 0);
      }
    }
    __syncthreads();
  }

  const size_t obase = (size_t)n * H * W * COUT;
  float sacc[NB], qacc[NB];
#pragma unroll
  for (int j = 0; j < NB; ++j) { sacc[j] = 0.f; qacc[j] = 0.f; }

#pragma unroll
  for (int i = 0; i < MT; ++i) {
#pragma unroll
    for (int j = 0; j < NB; ++j) {
      int oc = (ng * NB + j) * 32 + lm;
#pragma unroll
      for (int r = 0; r < 16; ++r) {
        int row = (r & 3) + 8 * (r >> 2) + 4 * lh;
        int oh = oh0 + trA[i] * 2 + (row >> 4);
        int ow = ow0 + tcA[i] * 16 + (row & 15);
        size_t pix = (size_t)(oh * W + ow);
        float v = acc[i][j][r];
        if constexpr (HAS_BASE) v += base[pix * COUT + oc];
        if constexpr (HAS_STATS) { sacc[j] += v; qacc[j] += v * v; }
        if constexpr (OUTF32) ((float*)outv)[obase + pix * COUT + oc] = v;
        else ((bf16*)outv)[obase + pix * COUT + oc] = __float2bfloat16(v);
      }
    }
  }

  if constexpr (HAS_STATS) {
    __shared__ float sred[2 * COUT];
    for (int i = tid; i < 2 * COUT; i += NW * 64) sred[i] = 0.f;
    __syncthreads();
#pragma unroll
    for (int j = 0; j < NB; ++j) {
      int oc = (ng * NB + j) * 32 + lm;
      atomicAdd(&sred[oc], sacc[j]);
      atomicAdd(&sred[COUT + oc], qacc[j]);
    }
    __syncthreads();
    for (int i = tid; i < 2 * COUT; i += NW * 64) atomicAdd(&stats[i], sred[i]);
  }
}

// ---------------- staging helpers (reg-staged path, unpadded inputs) ----------------
template<int NLD, int NTHR, int NGRAN, int IC, int CIN>
__device__ __forceinline__ void stage_issue(const bf16* __restrict__ in, size_t inbase,
    int ih0, int iw0, int HI, int WI, int ksl, int tid, uint4 (&stg)[NLD]) {
#pragma unroll
  for (int t = 0; t < NLD; ++t) {
    int idx = tid + t * NTHR;
    uint4 v = make_uint4(0u, 0u, 0u, 0u);
    if (idx < NGRAN) {
      int h8 = idx & 3; int pix = idx >> 2;
      int icl = pix % IC, ihl = pix / IC;
      int ih = ih0 + ihl, iw = iw0 + icl;
      if (ih >= 0 && ih < HI && iw >= 0 && iw < WI)
        v = *(const uint4*)(in + inbase + ((size_t)(ih * WI + iw)) * CIN + ksl * 32 + h8 * 8);
    }
    stg[t] = v;
  }
}

template<int NLD, int NTHR, int NGRAN, int IC, int ROWB, bool HAS_BN>
__device__ __forceinline__ void stage_commit(char* __restrict__ lds,
    const float* __restrict__ a, const float* __restrict__ b,
    int ih0, int iw0, int HI, int WI, int ksl, int tid, uint4 (&stg)[NLD]) {
#pragma unroll
  for (int t = 0; t < NLD; ++t) {
    int idx = tid + t * NTHR;
    if (idx < NGRAN) {
      int h8 = idx & 3; int pix = idx >> 2;
      int icl = pix % IC, ihl = pix / IC;
      uint4 v = stg[t];
      if constexpr (HAS_BN) {
        int ih = ih0 + ihl, iw = iw0 + icl;
        if (ih >= 0 && ih < HI && iw >= 0 && iw < WI) v = bn8<true>(v, a, b, ksl * 32 + h8 * 8);
      }
      int g = h8 ^ swz(icl);
      *(uint4*)(lds + (ihl * IC + icl) * ROWB + g * 16) = v;
    }
  }
}

// ---------------- 32x32x16 MFMA conv, reg-staged (BN-on-read path: conv3) ----------------
template<int COUT, int NT, int MT, int NB, int GR, int GC, int CIN,
         bool OUTF32, bool HAS_BN, bool HAS_STATS>
__global__ __launch_bounds__(((GR * GC) / MT) * (NT / NB) * 64)
void conv32_k(const bf16* __restrict__ in, const uint4* __restrict__ wf,
              void* __restrict__ outv,
              const float* __restrict__ bn_a, const float* __restrict__ bn_b,
              float* __restrict__ stats, int N, int H, int W) {
  constexpr int NW = ((GR * GC) / MT) * (NT / NB);
  constexpr int NTHR = NW * 64;
  constexpr int BR = GR * 2, BC = GC * 16;
  constexpr int IR = BR + 2, IC = BC + 2;
  constexpr int NSL = CIN / 32;
  constexpr int NGRAN = IR * IC * 4;
  constexpr int NLD = (NGRAN + NTHR - 1) / NTHR;
  __shared__ __align__(16) char lds[IR * IC * 64];

  const int tid = threadIdx.x;
  const int lane = tid & 63;
  const int wv = tid >> 6;
  const int lm = lane & 31, lh = lane >> 5;
  const int dh = lm >> 4, dw = lm & 15;
  constexpr int NG = NT / NB;
  const int mg = wv / NG, ng = wv % NG;

  const int tW = W / BC, tH = H / BR;
  const int tile = blockIdx.x % (tH * tW);
  const int n = blockIdx.x / (tH * tW);
  const int oh0 = (tile / tW) * BR, ow0 = (tile % tW) * BC;
  const int ih0 = oh0 - 1, iw0 = ow0 - 1;
  const size_t inbase = (size_t)n * H * W * CIN;

  int trA[MT], tcA[MT];
#pragma unroll
  for (int i = 0; i < MT; ++i) { int mt = mg * MT + i; trA[i] = mt / GC; tcA[i] = mt % GC; }

  f16v acc[MT][NB];
#pragma unroll
  for (int i = 0; i < MT; ++i)
#pragma unroll
    for (int j = 0; j < NB; ++j)
#pragma unroll
      for (int r = 0; r < 16; ++r) acc[i][j][r] = 0.f;

  {
    uint4 stg0[NLD];
    stage_issue<NLD, NTHR, NGRAN, IC, CIN>(in, inbase, ih0, iw0, H, W, 0, tid, stg0);
    stage_commit<NLD, NTHR, NGRAN, IC, 64, HAS_BN>(lds, bn_a, bn_b, ih0, iw0, H, W, 0, tid, stg0);
  }
  __syncthreads();

#pragma unroll
  for (int ksl = 0; ksl < NSL; ++ksl) {
    uint4 stgN[NLD];
    if (ksl + 1 < NSL)
      stage_issue<NLD, NTHR, NGRAN, IC, CIN>(in, inbase, ih0, iw0, H, W, ksl + 1, tid, stgN);

#pragma unroll
    for (int khw = 0; khw < 9; ++khw) {
      const int kh = khw / 3, kw = khw % 3;
      const uint4* wfp = wf + (size_t)(khw * 2 + (ksl >> 1)) * (NT * 256);
#pragma unroll
      for (int ks = 0; ks < 2; ++ks) {
        s8v Af[MT], Bf[NB];
#pragma unroll
        for (int i = 0; i < MT; ++i) {
          int rl = trA[i] * 2 + dh + kh;
          int cl = tcA[i] * 16 + dw + kw;
          int g = (ks * 2 + lh) ^ swz(cl);
          Af[i] = *(const s8v*)(lds + (rl * IC + cl) * 64 + g * 16);
        }
        int ks4 = (ksl & 1) * 2 + ks;
#pragma unroll
        for (int j = 0; j < NB; ++j)
          Bf[j] = as_s8v(wfp[(ks4 * NT + ng * NB + j) * 64 + lane]);
#pragma unroll
        for (int i = 0; i < MT; ++i)
#pragma unroll
          for (int j = 0; j < NB; ++j)
            acc[i][j] = __builtin_amdgcn_mfma_f32_32x32x16_bf16(Af[i], Bf[j], acc[i][j], 0, 0, 0);
      }
    }

    if (ksl + 1 < NSL) {
      __syncthreads();
      stage_commit<NLD, NTHR, NGRAN, IC, 64, HAS_BN>(lds, bn_a, bn_b, ih0, iw0, H, W, ksl + 1, tid, stgN);
      __syncthreads();
    }
  }

  const size_t obase = (size_t)n * H * W * COUT;
  float sacc[NB], qacc[NB];
#pragma unroll
  for (int j = 0; j < NB; ++j) { sacc[j] = 0.f; qacc[j] = 0.f; }

#pragma unroll
  for (int i = 0; i < MT; ++i) {
#pragma unroll
    for (int j = 0; j < NB; ++j) {
      int oc = (ng * NB + j) * 32 + lm;
#pragma unroll
      for (int r = 0; r < 16; ++r) {
        int row = (r & 3) + 8 * (r >> 2) + 4 * lh;
        int oh = oh0 + trA[i] * 2 + (row >> 4);
        int ow = ow0 + tcA[i] * 16 + (row & 15);
        size_t pix = (size_t)(oh * W + ow);
        float v = acc[i][j][r];
        if constexpr (HAS_STATS) { sacc[j] += v; qacc[j] += v * v; }
        if constexpr (OUTF32) ((float*)outv)[obase + pix * COUT + oc] = v;
        else ((bf16*)outv)[obase + pix * COUT + oc] = __float2bfloat16(v);
      }
    }
  }

  if constexpr (HAS_STATS) {
    __shared__ float sred[2 * COUT];
    for (int i = tid; i < 2 * COUT; i += NTHR) sred[i] = 0.f;
    __syncthreads();
#pragma unroll
    for (int j = 0; j < NB; ++j) {
      int oc = (ng * NB + j) * 32 + lm;
      atomicAdd(&sred[oc], sacc[j]);
      atomicAdd(&sred[COUT + oc], qacc[j]);
    }
    __syncthreads();
    for (int i = tid; i < 2 * COUT; i += NTHR) atomicAdd(&stats[i], sred[i]);
  }
}

// ---------------- 16x16x32 MFMA conv (stride 1 or 2), 32-ch slices ----------------
template<int COUT, int NT, int MT, int NB, int GR, int GC, int STRIDE,
         int CINT, bool HAS_BN, bool HAS_STATS>
__global__ __launch_bounds__(((GR * GC) / MT) * (NT / NB) * 64)
void conv16_k(const bf16* __restrict__ in, const uint4* __restrict__ wf,
              bf16* __restrict__ out, const float* __restrict__ bn_a,
              const float* __restrict__ bn_b, float* __restrict__ stats,
              int N, int HO, int WO, int HI, int WI) {
  constexpr int NW = ((GR * GC) / MT) * (NT / NB);
  constexpr int NTHR = NW * 64;
  constexpr int BR = GR, BC = GC * 16;
  constexpr int IR = STRIDE * (BR - 1) + 3;
  constexpr int IC = STRIDE * (BC - 1) + 3 + (STRIDE == 2 ? 1 : 0);
  constexpr int ROWB = (STRIDE == 2) ? 80 : 64;
  constexpr int NSL = CINT / 32;
  constexpr int NGRAN = IR * IC * 4;
  constexpr int NLD = (NGRAN + NTHR - 1) / NTHR;
  __shared__ __align__(16) char lds[IR * IC * ROWB];

  const int tid = threadIdx.x;
  const int lane = tid & 63;
  const int wv = tid >> 6;
  const int lm = lane & 15, lg = lane >> 4;
  constexpr int NG = NT / NB;
  const int mg = wv / NG, ng = wv % NG;

  const int tW = WO / BC, tH = HO / BR;
  const int tile = blockIdx.x % (tH * tW);
  const int n = blockIdx.x / (tH * tW);
  const int oh0 = (tile / tW) * BR, ow0 = (tile % tW) * BC;
  const int ih0 = STRIDE * oh0 - 1, iw0 = STRIDE * ow0 - 1;
  const size_t inbase = (size_t)n * HI * WI * CINT;

  int trA[MT], tcA[MT];
#pragma unroll
  for (int i = 0; i < MT; ++i) { int mt = mg * MT + i; trA[i] = mt / GC; tcA[i] = mt % GC; }

  f4v acc[MT][NB];
#pragma unroll
  for (int i = 0; i < MT; ++i)
#pragma unroll
    for (int j = 0; j < NB; ++j)
#pragma unroll
      for (int r = 0; r < 4; ++r) acc[i][j][r] = 0.f;

  {
    uint4 stg0[NLD];
    stage_issue<NLD, NTHR, NGRAN, IC, CINT>(in, inbase, ih0, iw0, HI, WI, 0, tid, stg0);
    stage_commit<NLD, NTHR, NGRAN, IC, ROWB, HAS_BN>(lds, bn_a, bn_b, ih0, iw0, HI, WI, 0, tid, stg0);
  }
  __syncthreads();

#pragma unroll
  for (int ksl = 0; ksl < NSL; ++ksl) {
    uint4 stgN[NLD];
    if (ksl + 1 < NSL)
      stage_issue<NLD, NTHR, NGRAN, IC, CINT>(in, inbase, ih0, iw0, HI, WI, ksl + 1, tid, stgN);

#pragma unroll
    for (int khw = 0; khw < 9; ++khw) {
      const int kh = khw / 3, kw = khw % 3;
      const uint4* wfp = wf + (size_t)(khw * NSL + ksl) * (NT * 64);
      s8v Af[MT], Bf[NB];
#pragma unroll
      for (int i = 0; i < MT; ++i) {
        int rl = STRIDE * trA[i] + kh;
        int cl = STRIDE * (tcA[i] * 16 + lm) + kw;
        int g = lg ^ swz(cl);
        Af[i] = *(const s8v*)(lds + (rl * IC + cl) * ROWB + g * 16);
      }
#pragma unroll
      for (int j = 0; j < NB; ++j)
        Bf[j] = as_s8v(wfp[(ng * NB + j) * 64 + lane]);
#pragma unroll
      for (int i = 0; i < MT; ++i)
#pragma unroll
        for (int j = 0; j < NB; ++j)
          acc[i][j] = __builtin_amdgcn_mfma_f32_16x16x32_bf16(Af[i], Bf[j], acc[i][j], 0, 0, 0);
    }

    if (ksl + 1 < NSL) {
      __syncthreads();
      stage_commit<NLD, NTHR, NGRAN, IC, ROWB, HAS_BN>(lds, bn_a, bn_b, ih0, iw0, HI, WI, ksl + 1, tid, stgN);
      __syncthreads();
    }
  }

  const size_t obase = (size_t)n * HO * WO * COUT;
  float sacc[NB], qacc[NB];
#pragma unroll
  for (int j = 0; j < NB; ++j) { sacc[j] = 0.f; qacc[j] = 0.f; }

#pragma unroll
  for (int i = 0; i < MT; ++i) {
#pragma unroll
    for (int j = 0; j < NB; ++j) {
      int oc = (ng * NB + j) * 16 + lm;
#pragma unroll
      for (int r = 0; r < 4; ++r) {
        int oh = oh0 + trA[i];
        int ow = ow0 + tcA[i] * 16 + lg * 4 + r;
        float v = acc[i][j][r];
        if constexpr (HAS_STATS) { sacc[j] += v; qacc[j] += v * v; }
        out[obase + (size_t)(oh * WO + ow) * COUT + oc] = __float2bfloat16(v);
      }
    }
  }

  if constexpr (HAS_STATS) {
    __shared__ float sred[2 * COUT];
    for (int i = tid; i < 2 * COUT; i += NTHR) sred[i] = 0.f;
    __syncthreads();
#pragma unroll
    for (int j = 0; j < NB; ++j) {
      int oc = (ng * NB + j) * 16 + lm;
      atomicAdd(&sred[oc], sacc[j]);
      atomicAdd(&sred[COUT + oc], qacc[j]);
    }
    __syncthreads();
    for (int i = tid; i < 2 * COUT; i += NTHR) atomicAdd(&stats[i], sred[i]);
  }
}

// ---------------- deconv (ConvTranspose2d k4 s2 p1, 64->32) via 16x16x32 ----------------
__global__ __launch_bounds__(256)
void deconv16_k(const bf16* __restrict__ in, const uint4* __restrict__ wf5,
                bf16* __restrict__ out, const float* __restrict__ a4,
                const float* __restrict__ b4, float* __restrict__ stats) {
  constexpr int IR = 6, IC = 50, INB = IR * IC * 128;
  __shared__ __align__(16) char lds[INB];
  __shared__ float sred[64];
  const int tid = threadIdx.x;
  const int lane = tid & 63, wv = tid >> 6;
  const int lm = lane & 15, lg = lane >> 4;
  const int n = blockIdx.x / 6;
  const int qh0 = (blockIdx.x % 6) * 4;
  const size_t ibase = (size_t)n * HW2 * 64;

  for (int idx = tid; idx < 64; idx += 256) sred[idx] = 0.f;

  for (int idx = tid; idx < IR * IC * 8; idx += 256) {
    int h8 = idx & 7; int icl = (idx >> 3) % IC; int ihl = (idx >> 3) / IC;
    int ih = qh0 - 1 + ihl, iw = -1 + icl;
    uint4 v = make_uint4(0u, 0u, 0u, 0u);
    if (ih >= 0 && ih < H2 && iw >= 0 && iw < W2) {
      v = *(const uint4*)(in + ibase + ((size_t)(ih * W2 + iw)) * 64 + h8 * 8);
      v = bn8<true>(v, a4, b4, h8 * 8);
    }
    int bbyte = (ihl * IC + icl) * 128 + h8 * 16;
    bbyte ^= (icl & 7) << 4;
    *(uint4*)(lds + bbyte) = v;
  }
  __syncthreads();

  int trA[3], tcA[3];
#pragma unroll
  for (int i = 0; i < 3; ++i) { int mt = wv * 3 + i; trA[i] = mt / 3; tcA[i] = mt % 3; }

  float sacc[2], qacc[2];
  sacc[0] = sacc[1] = qacc[0] = qacc[1] = 0.f;

  for (int p = 0; p < 4; ++p) {
    const int ph = p >> 1, pw = p & 1;
    f4v acc[3][2];
#pragma unroll
    for (int i = 0; i < 3; ++i)
#pragma unroll
      for (int j = 0; j < 2; ++j)
#pragma unroll
        for (int r = 0; r < 4; ++r) acc[i][j][r] = 0.f;
#pragma unroll
    for (int ks = 0; ks < 8; ++ks) {
      int t = ks >> 2, u = (ks >> 1) & 1, cb = ks & 1;
      s8v Af[3], Bf[2];
#pragma unroll
      for (int i = 0; i < 3; ++i) {
        int rl = trA[i] + t + ph;
        int cl = tcA[i] * 16 + lm + u + pw;
        int bbyte = (rl * IC + cl) * 128 + cb * 64 + lg * 16;
        bbyte ^= (cl & 7) << 4;
        Af[i] = *(const s8v*)(lds + bbyte);
      }
#pragma unroll
      for (int j = 0; j < 2; ++j)
        Bf[j] = as_s8v(wf5[p * 1024 + (ks * 2 + j) * 64 + lg * 16 + lm]);
#pragma unroll
      for (int i = 0; i < 3; ++i)
#pragma unroll
        for (int j = 0; j < 2; ++j)
          acc[i][j] = __builtin_amdgcn_mfma_f32_16x16x32_bf16(Af[i], Bf[j], acc[i][j], 0, 0, 0);
    }
#pragma unroll
    for (int i = 0; i < 3; ++i) {
#pragma unroll
      for (int j = 0; j < 2; ++j) {
        int oc = j * 16 + lm;
#pragma unroll
        for (int r = 0; r < 4; ++r) {
          int qh = qh0 + trA[i];
          int qw = tcA[i] * 16 + lg * 4 + r;
          int oh = 2 * qh + ph, ow = 2 * qw + pw;
          float v = acc[i][j][r];
          sacc[j] += v; qacc[j] += v * v;
          out[((size_t)n * HW + oh * Ww + ow) * 32 + oc] = __float2bfloat16(v);
        }
      }
    }
  }

  __syncthreads();
#pragma unroll
  for (int j = 0; j < 2; ++j) {
    int oc = j * 16 + lm;
    atomicAdd(&sred[oc], sacc[j]);
    atomicAdd(&sred[32 + oc], qacc[j]);
  }
  __syncthreads();
  for (int i = tid; i < 64; i += 256) atomicAdd(&stats[i], sred[i]);
}

// ---------------- BN finalize ----------------
__global__ void bnfin_k(const float* __restrict__ sums, const float* __restrict__ gamma,
                        const float* __restrict__ beta, float* __restrict__ ab, int C, float invCnt) {
  int c = blockIdx.x * blockDim.x + threadIdx.x;
  if (c >= C) return;
  float mean = sums[c] * invCnt;
  float var = sums[C + c] * invCnt - mean * mean;
  float a = gamma[c] * rsqrtf(var + 1e-5f);
  ab[c] = a;
  ab[C + c] = beta[c] - mean * a;
}

// ---------------- conv6 (32->1, 3x3, fused bn5): LDS-staged ----------------
__global__ __launch_bounds__(384)
void conv6_k(const bf16* __restrict__ y5, const float* __restrict__ w6,
             const float* __restrict__ b6, const float* __restrict__ a5,
             const float* __restrict__ bb5, float* __restrict__ y6) {
  __shared__ __align__(16) char l6[6 * 98 * 64];
  __shared__ float w6s[288];
  const int tid = threadIdx.x;
  const int n = blockIdx.x / 12, qh0 = (blockIdx.x % 12) * 4;
  if (tid < 288) w6s[tid] = w6[tid];
  for (int idx = tid; idx < 6 * 98 * 4; idx += 384) {
    int g = idx & 3, cell = idx >> 2;
    int icl = cell % 98, ihl = cell / 98;
    int ih = qh0 - 1 + ihl, iw = icl - 1;
    uint4 v = make_uint4(0u, 0u, 0u, 0u);
    if (ih >= 0 && ih < Hh && iw >= 0 && iw < Ww) {
      v = *(const uint4*)(y5 + ((size_t)n * HW + ih * Ww + iw) * 32 + g * 8);
      v = bn8<true>(v, a5, bb5, g * 8);
    }
    *(uint4*)(l6 + cell * 64 + (g ^ swz6(cell)) * 16) = v;
  }
  __syncthreads();

  const int trow = tid / 96, ow = tid % 96;
  float acc = b6[0];
#pragma unroll
  for (int kh = 0; kh < 3; ++kh) {
#pragma unroll
    for (int kw = 0; kw < 3; ++kw) {
      int cell = (trow + kh) * 98 + ow + kw;
      int khw = kh * 3 + kw;
#pragma unroll
      for (int c8 = 0; c8 < 4; ++c8) {
        union { uint4 u; unsigned short h[8]; } X;
        X.u = *(const uint4*)(l6 + cell * 64 + (c8 ^ swz6(cell)) * 16);
#pragma unroll
        for (int i = 0; i < 8; ++i)
          acc += bf2f(X.h[i]) * w6s[(c8 * 8 + i) * 9 + khw];
      }
    }
  }
  y6[(size_t)n * HW + (qh0 + trow) * Ww + ow] = acc;
}

// ---------------- DAP: LDS-staged 49x64 tiles ----------------
__global__ __launch_bounds__(256)
void dap_k(const float* __restrict__ y6, const float* __restrict__ dap, float* __restrict__ out) {
  __shared__ float sh[49 * 64];
  const int tid = threadIdx.x;
  const int b = blockIdx.x / 72, t0 = (blockIdx.x % 72) * 64;
  for (int idx = tid; idx < 49 * 64; idx += 256) {
    int d = idx >> 6, x = idx & 63;
    sh[idx] = y6[((size_t)(b * 49 + d)) * HW + t0 + x];
  }
  __syncthreads();
  for (int oidx = tid; oidx < 49 * 64; oidx += 256) {
    int e = oidx >> 6, x = oidx & 63;
    float s = 0.f;
#pragma unroll 7
    for (int d = 0; d < 49; ++d) s += dap[e * 49 + d] * sh[(d << 6) + x];
    out[((size_t)(b * 49 + e)) * HW + t0 + x] = s;
  }
}

// ---------------- host launch ----------------
extern "C" void kernel_launch(void* const* d_in, const int* in_sizes, int n_in,
                              void* d_out, int out_size, void* d_ws, size_t ws_size,
                              hipStream_t stream) {
  const float* f1 = (const float*)d_in[0];
  const float* f2 = (const float*)d_in[1];
  const float* coords = (const float*)d_in[2];
  const float* w1 = (const float*)d_in[3];
  const float* g1 = (const float*)d_in[4];
  const float* b1 = (const float*)d_in[5];
  const float* w2 = (const float*)d_in[6];
  const float* g2 = (const float*)d_in[7];
  const float* b2 = (const float*)d_in[8];
  const float* w3 = (const float*)d_in[9];
  const float* g3 = (const float*)d_in[10];
  const float* b3 = (const float*)d_in[11];
  const float* w4 = (const float*)d_in[12];
  const float* g4 = (const float*)d_in[13];
  const float* b4 = (const float*)d_in[14];
  const float* w5 = (const float*)d_in[15];
  const float* g5 = (const float*)d_in[16];
  const float* b5 = (const float*)d_in[17];
  const float* w6 = (const float*)d_in[18];
  const float* b6 = (const float*)d_in[19];
  const float* dap = (const float*)d_in[20];
  float* out = (float*)d_out;
  char* ws = (char*)d_ws;
  if (ws_size < WS_NEEDED) return;

  uint4* wf1a = (uint4*)(ws + off_wf1a);
  uint4* wf1b = (uint4*)(ws + off_wf1b);
  uint4* wf3 = (uint4*)(ws + off_wf3);
  uint4* wf2 = (uint4*)(ws + off_wf2);
  uint4* wf4 = (uint4*)(ws + off_wf4);
  uint4* wf5 = (uint4*)(ws + off_wf5);
  bf16* f1t = (bf16*)(ws + off_f1t);
  float* y1a = (float*)(ws + off_y1a);
  bf16* f2tb = (bf16*)(ws + off_f2tb);
  bf16* f2s = (bf16*)(ws + off_f2s);
  bf16* y1 = (bf16*)(ws + off_y1);
  bf16* y2 = (bf16*)(ws + off_y2);
  bf16* y3 = (bf16*)(ws + off_y3);
  bf16* y4 = (bf16*)(ws + off_y4);
  bf16* y5 = (bf16*)(ws + off_y5);
  float* y6 = (float*)(ws + off_y6);
  float* st0 = (float*)(ws + off_stats) + 0 * 512;
  float* st1 = (float*)(ws + off_stats) + 1 * 512;
  float* st2 = (float*)(ws + off_stats) + 2 * 512;
  float* st3 = (float*)(ws + off_stats) + 3 * 512;
  float* st4 = (float*)(ws + off_stats) + 4 * 512;

  zero_k<<<10, 256, 0, stream>>>((float*)(ws + off_stats), 2560);
  zero_k<<<2451, 256, 0, stream>>>((float*)f1t, 627200);   // zero padded f1t

  tr_f2b_k<<<576, 256, 0, stream>>>(f2, f2tb);
  tr_f1_k<<<576, 256, 0, stream>>>(f1, f1t);
  prep32_k<<<54, 256, 0, stream>>>(w1, wf1a, 3, 256, 0);
  prep32_k<<<54, 256, 0, stream>>>(w1, wf1b, 3, 256, 128);
  prep32_k<<<72, 256, 0, stream>>>(w3, wf3, 4, 128, 0);
  prep16_k<<<54, 256, 0, stream>>>(w2, wf2, 8, 96, 3, 32, 1);
  prep16_k<<<36, 256, 0, stream>>>(w4, wf4, 4, 128, 4, 32, 1);
  prep_w5_k<<<16, 256, 0, stream>>>(w5, wf5);

  border0_k<<<56, 256, 0, stream>>>(f2s);   // zero halo once (persists across halves)

  // conv1 f1-half (shared across displacements), f32 NHWC out
  conv32gll_k<96, 3, 2, 3, 4, 2, true, false, false><<<36, 256, 0, stream>>>(
      f1t, wf1a, y1a, nullptr, nullptr, 2, Hh, Ww);

  // per-b halves: sample then conv1 f2-half (+base, fused BN1 stats)
  for (int half = 0; half < 2; ++half) {
    sample_k<<<1764, 256, 0, stream>>>(f2tb, coords, f2s, half);
    conv32gll_k<96, 3, 2, 3, 4, 2, false, true, true><<<882, 256, 0, stream>>>(
        f2s, wf1b, y1 + (size_t)half * 49 * HW * 96, y1a + (size_t)half * HW * 96,
        st0, 49, Hh, Ww);
  }
  bnfin_k<<<1, 256, 0, stream>>>(st0, g1, b1, st0 + 256, 96, 1.f / (98.f * 4608.f));

  // conv2 stride 2 (bn1 fused on input staging), fused BN2 stats
  conv16_k<128, 8, 3, 4, 2, 3, 2, 96, true, true><<<1176, 256, 0, stream>>>(
      y1, wf2, y2, st0 + 256, st0 + 256 + 96, st1, Nn, H2, W2, Hh, Ww);
  bnfin_k<<<1, 256, 0, stream>>>(st1, g2, b2, st1 + 256, 128, 1.f / (98.f * 1152.f));

  // conv3 (bn2 fused), fused BN3 stats
  conv32_k<128, 4, 3, 2, 2, 3, 128, false, true, true><<<588, 256, 0, stream>>>(
      y2, wf3, y3, st1 + 256, st1 + 256 + 128, st2, Nn, H2, W2);
  bnfin_k<<<1, 256, 0, stream>>>(st2, g3, b3, st2 + 256, 128, 1.f / (98.f * 1152.f));

  // conv4 (bn3 fused), fused BN4 stats
  conv16_k<64, 4, 3, 4, 4, 3, 1, 128, true, true><<<588, 256, 0, stream>>>(
      y3, wf4, y4, st2 + 256, st2 + 256 + 128, st3, Nn, H2, W2, H2, W2);
  bnfin_k<<<1, 256, 0, stream>>>(st3, g4, b4, st3 + 256, 64, 1.f / (98.f * 1152.f));

  // deconv (bn4 fused), fused BN5 stats
  deconv16_k<<<588, 256, 0, stream>>>(y4, wf5, y5, st3 + 256, st3 + 256 + 64, st4);
  bnfin_k<<<1, 256, 0, stream>>>(st4, g5, b5, st4 + 256, 32, 1.f / (98.f * 4608.f));

  // conv6 (bn5 fused at staging) + bias -> f32
  conv6_k<<<1176, 384, 0, stream>>>(y5, w6, b6, st4 + 256, st4 + 256 + 32, y6);

  // DAP
  dap_k<<<144, 256, 0, stream>>>(y6, dap, out);
}